// Round 2
// baseline (1219.086 us; speedup 1.0000x reference)
//
#include <hip/hip_runtime.h>
#include <hip/hip_fp16.h>

// N=512, C=3, T=300, V=25, M=2, F=150, H=100, gates=4H=400
// x element (n,c,t,v,m) at n*45000 + c*15000 + t*50 + (v*2+m)
// Thread->gate-row map: r(t) = (t&3)*100 + (t>>2), t<400 (i,f,g,o of cell j on adjacent lanes)

// ws layout (BYTE offsets):
#define B_W2P   0u          // uint[50][512]  dec folded Whh+Wih@fcW, f16-pair packed
#define B_WDP   102400u     // uint[50][512]  dec Whh (step-1)
#define B_WEP   204800u     // uint[50][512]  enc Whh
#define B_PIH   307200u     // uint[75][512]  enc Wih f16 pairs
#define B_BENC  460800u     // float[512]
#define B_B1    462848u     // float[512]
#define B_BEFF  464896u     // float[512]
#define B_HIST  466944u     // ushort hist[512][29952]
#define HIST_STRIDE 29952
#define B_XG    31137792u   // ushort xg[512][150][400]  (61,440,000 B == old npass=2 footprint)
// Phase-0 carry state is parked at the head of each sample's hist region:
//   h149 (f16) at histn[0..99]; c149 (f32) at histn+128 ushorts (256B offset).
// Safe: phase-1 reads it at block start; decoder steps 1..4 overwrite those
// slots later in the SAME block, before emit consumes hist.

typedef _Float16 h2_t __attribute__((ext_vector_type(2)));

#if defined(__has_builtin)
#if __has_builtin(__builtin_amdgcn_fdot2)
#define HAS_FDOT2 1
#endif
#endif

__device__ __forceinline__ float fdot2u(unsigned a, unsigned b, float c) {
#ifdef HAS_FDOT2
  return __builtin_amdgcn_fdot2(__builtin_bit_cast(h2_t, a), __builtin_bit_cast(h2_t, b), c, false);
#else
  float al = __half2float(__ushort_as_half((unsigned short)(a & 0xffffu)));
  float ah = __half2float(__ushort_as_half((unsigned short)(a >> 16)));
  float bl = __half2float(__ushort_as_half((unsigned short)(b & 0xffffu)));
  float bh = __half2float(__ushort_as_half((unsigned short)(b >> 16)));
  return fmaf(ah, bh, fmaf(al, bl, c));
#endif
}

__device__ __forceinline__ unsigned pack2f(float a, float b) {
  return (unsigned)__half_as_ushort(__float2half(a)) |
         ((unsigned)__half_as_ushort(__float2half(b)) << 16);
}

__device__ __forceinline__ float fast_sig(float x) {
  float e = __builtin_amdgcn_exp2f(x * -1.442695040888963f);
  return __builtin_amdgcn_rcpf(1.f + e);
}
__device__ __forceinline__ float fast_tanh(float x) {
  float e = __builtin_amdgcn_exp2f(x * -2.885390081777926f);
  return fmaf(2.f, __builtin_amdgcn_rcpf(1.f + e), -1.f);
}

// activate-then-shuffle tail: on leader lanes (ty==0) act=sig(i), v1=sig(f),
// v2=tanh(g), v3=sig(o). Non-leader lanes compute garbage (discarded).
__device__ __forceinline__ float lstm_tail(float acc, int ty, float& c) {
  float sg = fast_sig(acc);
  float th = fast_tanh(acc);
  float act = (ty == 2) ? th : sg;
  float v1 = __shfl_xor(act, 1);
  float v2 = __shfl_xor(act, 2);
  float v3 = __shfl_xor(v1, 2);
  c = fmaf(v1, c, act * v2);
  return v3 * fast_tanh(c);
}

// K=100 f16 dot: 12 uint4 + 1 uint2 LDS reads, 50 fdot2, 4 accumulators
__device__ __forceinline__ float dot100(const unsigned short* hb, const unsigned* wp) {
  const uint4* h4 = (const uint4*)hb;
  float a0 = 0.f, a1 = 0.f, a2 = 0.f, a3 = 0.f;
#pragma unroll
  for (int ch = 0; ch < 12; ++ch) {
    uint4 v = h4[ch];
    a0 = fdot2u(wp[4 * ch + 0], v.x, a0);
    a1 = fdot2u(wp[4 * ch + 1], v.y, a1);
    a2 = fdot2u(wp[4 * ch + 2], v.z, a2);
    a3 = fdot2u(wp[4 * ch + 3], v.w, a3);
  }
  uint2 v2 = *(const uint2*)(hb + 96);
  a0 = fdot2u(wp[48], v2.x, a0);
  a1 = fdot2u(wp[49], v2.y, a1);
  return (a0 + a1) + (a2 + a3);
}

// ---------------- prep ----------------
__global__ void prep(const float* __restrict__ dWih, const float* __restrict__ dWhh,
                     const float* __restrict__ dbih, const float* __restrict__ dbhh,
                     const float* __restrict__ eWih, const float* __restrict__ eWhh,
                     const float* __restrict__ ebih, const float* __restrict__ ebhh,
                     const float* __restrict__ fcW,  const float* __restrict__ fcb,
                     char* __restrict__ wsb)
{
  int idx = blockIdx.x * 256 + threadIdx.x;
  if (idx < 25600) {                       // packed weight rows (pairs)
    int q = idx >> 9, t = idx & 511;
    unsigned w2p = 0, wdp = 0, wep = 0;
    if (t < 400) {
      int r = (t & 3) * 100 + (t >> 2);
      int j0 = 2 * q, j1 = 2 * q + 1;
      float wd0 = dWhh[r * 100 + j0], wd1 = dWhh[r * 100 + j1];
      float we0 = eWhh[r * 100 + j0], we1 = eWhh[r * 100 + j1];
      float s0 = 0.f, s1 = 0.f;
      for (int f = 0; f < 150; ++f) {
        float a = dWih[r * 150 + f];
        s0 = fmaf(a, fcW[f * 100 + j0], s0);
        s1 = fmaf(a, fcW[f * 100 + j1], s1);
      }
      w2p = pack2f(wd0 + s0, wd1 + s1);
      wdp = pack2f(wd0, wd1);
      wep = pack2f(we0, we1);
    }
    ((unsigned*)(wsb + B_W2P))[idx] = w2p;
    ((unsigned*)(wsb + B_WDP))[idx] = wdp;
    ((unsigned*)(wsb + B_WEP))[idx] = wep;
  } else if (idx < 25600 + 38400) {        // packed f16 enc_Wih
    int k = idx - 25600; int d = k >> 9, t = k & 511;
    unsigned pk = 0;
    if (t < 400) {
      int r = (t & 3) * 100 + (t >> 2);
      pk = pack2f(eWih[r * 150 + 2 * d], eWih[r * 150 + 2 * d + 1]);
    }
    ((unsigned*)(wsb + B_PIH))[k] = pk;
  } else if (idx < 25600 + 38400 + 512) {  // biases
    int t = idx - (25600 + 38400);
    float be = 0.f, b1 = 0.f, bf = 0.f;
    if (t < 400) {
      int r = (t & 3) * 100 + (t >> 2);
      be = ebih[r] + ebhh[r];
      b1 = dbih[r] + dbhh[r];
      float acc = 0.f;
      for (int f = 0; f < 150; ++f) acc = fmaf(dWih[r * 150 + f], fcb[f], acc);
      bf = b1 + acc;
    }
    ((float*)(wsb + B_BENC))[t] = be;
    ((float*)(wsb + B_B1))[t]   = b1;
    ((float*)(wsb + B_BEFF))[t] = bf;
  }
}

// ---------------- pre: xg[n][tl][g] = enc_Wih(f16) @ x_{tbase+tl}, tl<150 ----------------
__global__ __launch_bounds__(512, 4)
void pre(const float* __restrict__ x, const char* __restrict__ wsb,
         unsigned short* __restrict__ xg, int tbase)
{
  const int tid = threadIdx.x;
  const int n = blockIdx.x;
  __shared__ unsigned short xls[150 * 160];

  unsigned wih[75];
  const unsigned* pih = (const unsigned*)(wsb + B_PIH);
#pragma unroll
  for (int d = 0; d < 75; ++d) wih[d] = pih[(d << 9) + tid];

  const float* xb = x + (size_t)n * 45000;
  unsigned short* xgr = xg + (size_t)n * 60000 + ((tid < 400) ? tid : 0);
  const bool on = tid < 400;

  for (int d = tid; d < 150 * 160; d += 512) {
    int tl = d / 160, f = d - tl * 160;
    float v = 0.f;
    if (f < 150) {
      int c = f / 50, q = f - c * 50;
      v = xb[c * 15000 + (tbase + tl) * 50 + q];
    }
    xls[tl * 160 + f] = __half_as_ushort(__float2half(v));
  }
  __syncthreads();
  if (on) {
    for (int tl = 0; tl < 150; ++tl) {
      const uint4* row = (const uint4*)(xls + tl * 160);
      float a0 = 0.f, a1 = 0.f, a2 = 0.f, a3 = 0.f;
#pragma unroll
      for (int ch = 0; ch < 18; ++ch) {
        uint4 v = row[ch];
        a0 = fdot2u(wih[4 * ch + 0], v.x, a0);
        a1 = fdot2u(wih[4 * ch + 1], v.y, a1);
        a2 = fdot2u(wih[4 * ch + 2], v.z, a2);
        a3 = fdot2u(wih[4 * ch + 3], v.w, a3);
      }
      uint4 v = row[18];
      a0 = fdot2u(wih[72], v.x, a0);
      a1 = fdot2u(wih[73], v.y, a1);
      a2 = fdot2u(wih[74], v.z, a2);
      float a = (a0 + a1) + (a2 + a3);
      xgr[(size_t)tl * 400] = __half_as_ushort(__float2half(a));
    }
  }
}

// ---------------- recurrent: time-split, 512 blocks (all samples), 2 phases ----------------
// phase 0: encoder steps 0..149, park (h149,c149) in hist head
// phase 1: restore, encoder steps 150..299, then 299 decoder steps + hist
__global__ __launch_bounds__(512, 4)
void recurrent(const unsigned short* __restrict__ xg, char* __restrict__ wsb, int phase)
{
  const int t  = threadIdx.x;
  const int n  = blockIdx.x;
  const int j  = t >> 2, ty = t & 3;
  const bool leader = (t < 400) && (ty == 0);
  __shared__ unsigned short hh[2][112];

  const unsigned* WEP = (const unsigned*)(wsb + B_WEP);
  const unsigned* WDP = (const unsigned*)(wsb + B_WDP);
  const unsigned* W2P = (const unsigned*)(wsb + B_W2P);

  unsigned wp[50];
#pragma unroll
  for (int q = 0; q < 50; ++q) wp[q] = WEP[(q << 9) + t];

  const float benc = ((const float*)(wsb + B_BENC))[t];
  const float b1g  = ((const float*)(wsb + B_B1))[t];
  const float beff = ((const float*)(wsb + B_BEFF))[t];
  unsigned short* histn = (unsigned short*)(wsb + B_HIST) + (size_t)n * HIST_STRIDE;
  float* stc = (float*)(histn + 128);   // 100 f32 carry-c, 256B into hist region
  const unsigned short* xgr = xg + (size_t)n * 60000 + ((t < 400) ? t : 0);
  float c = 0.f;

  if (phase == 0) {
    // encoder step 0 (h=0): acc = benc + xg0
    unsigned short p1 = xgr[400];
    {
      float acc = benc + __half2float(__ushort_as_half(xgr[0]));
      float hn = lstm_tail(acc, ty, c);
      if (leader) hh[1][j] = __half_as_ushort(__float2half(hn));
      __syncthreads();
    }
    // encoder steps 1..149
    for (int ts = 1; ts < 150; ++ts) {
      const int rd = ts & 1, wr = rd ^ 1;
      unsigned short pn = xgr[(size_t)((ts + 1 < 150) ? ts + 1 : 149) * 400];
      float acc = benc + __half2float(__ushort_as_half(p1)) + dot100(hh[rd], wp);
      float hn = lstm_tail(acc, ty, c);
      if (leader) hh[wr][j] = __half_as_ushort(__float2half(hn));
      __syncthreads();
      p1 = pn;
    }
    // h149 is in hh[0] (f16); park state in hist head
    if (t < 100) histn[t] = hh[0][t];
    if (leader)  stc[j] = c;
    return;
  }

  // ---- phase 1: restore carry ----
  if (t < 100) hh[0][t] = histn[t];
  if (t < 400) c = stc[j];
  unsigned short p1 = xgr[0];
  __syncthreads();

  // encoder steps 150..299 (xg half-2 at local index ts-150)
  for (int ts = 150; ts < 300; ++ts) {
    const int rd = ts & 1, wr = rd ^ 1;
    const int idx = ts - 150;
    unsigned short pn = xgr[(size_t)((idx + 1 < 150) ? idx + 1 : 149) * 400];
    float acc = benc + __half2float(__ushort_as_half(p1)) + dot100(hh[rd], wp);
    float hn = lstm_tail(acc, ty, c);
    if (leader) hh[wr][j] = __half_as_ushort(__float2half(hn));
    __syncthreads();
    p1 = pn;
  }

  // decoder step 1: plain Whh (input zeros); enc h is in hh[0]
#pragma unroll
  for (int q = 0; q < 50; ++q) wp[q] = WDP[(q << 9) + t];
  {
    float acc = b1g + dot100(hh[0], wp);
    float hn = lstm_tail(acc, ty, c);
    if (leader) {
      hh[1][j] = __half_as_ushort(__float2half(hn));
      histn[j] = __half_as_ushort(__float2half(hn));
    }
    __syncthreads();
  }
  // decoder steps 2..299: folded W2
#pragma unroll
  for (int q = 0; q < 50; ++q) wp[q] = W2P[(q << 9) + t];
  for (int s = 2; s <= 299; ++s) {
    const int rd = (299 + s) & 1, wr = rd ^ 1;
    float acc = beff + dot100(hh[rd], wp);
    float hn = lstm_tail(acc, ty, c);
    if (leader) {
      hh[wr][j] = __half_as_ushort(__float2half(hn));
      histn[(s - 1) * 100 + j] = __half_as_ushort(__float2half(hn));
    }
    __syncthreads();
  }
}

// ---------------- emit: out[n][t] = fcW @ h_{t-1} + fcb ----------------
__global__ __launch_bounds__(192, 4)
void emit(const char* __restrict__ wsb, const float* __restrict__ fcW,
          const float* __restrict__ fcb, float* __restrict__ out)
{
  const int f = threadIdx.x;
  const int n = blockIdx.x;
  const int z = blockIdx.y;
  __shared__ unsigned short hl[15008];

  const uint4* src = (const uint4*)((const unsigned short*)(wsb + B_HIST) +
                                    (size_t)n * HIST_STRIDE + z * 15000);
  for (int k = f; k < 1875; k += 192) ((uint4*)hl)[k] = src[k];

  const bool on = f < 150;
  unsigned fw[50];
  float bias = 0.f;
  if (on) {
    const float* fp = fcW + f * 100;
#pragma unroll
    for (int q = 0; q < 50; ++q) fw[q] = pack2f(fp[2 * q], fp[2 * q + 1]);
    bias = fcb[f];
  }
  __syncthreads();

  if (!on) return;
  const int cc = f / 50, r = f - cc * 50;
  float* ob = out + (size_t)n * 45000 + cc * 15000 + r;
  if (z == 0) ob[0] = 0.f;
  const int rows = z ? 149 : 150;
  for (int tl = 0; tl < rows; ++tl) {
    const uint4* row = (const uint4*)(hl + tl * 100);
    float a0 = bias, a1 = 0.f, a2 = 0.f, a3 = 0.f;
#pragma unroll
    for (int ch = 0; ch < 12; ++ch) {
      uint4 v = row[ch];
      a0 = fdot2u(fw[4 * ch + 0], v.x, a0);
      a1 = fdot2u(fw[4 * ch + 1], v.y, a1);
      a2 = fdot2u(fw[4 * ch + 2], v.z, a2);
      a3 = fdot2u(fw[4 * ch + 3], v.w, a3);
    }
    uint2 v2 = *(const uint2*)(hl + tl * 100 + 96);
    a0 = fdot2u(fw[48], v2.x, a0);
    a1 = fdot2u(fw[49], v2.y, a1);
    const int tt = z * 150 + tl + 1;
    ob[tt * 50] = (a0 + a1) + (a2 + a3);
  }
}

extern "C" void kernel_launch(void* const* d_in, const int* in_sizes, int n_in,
                              void* d_out, int out_size, void* d_ws, size_t ws_size,
                              hipStream_t stream) {
  const float* x    = (const float*)d_in[0];
  const float* eWih = (const float*)d_in[1];
  const float* eWhh = (const float*)d_in[2];
  const float* ebih = (const float*)d_in[3];
  const float* ebhh = (const float*)d_in[4];
  const float* dWih = (const float*)d_in[5];
  const float* dWhh = (const float*)d_in[6];
  const float* dbih = (const float*)d_in[7];
  const float* dbhh = (const float*)d_in[8];
  const float* fcW  = (const float*)d_in[9];
  const float* fcb  = (const float*)d_in[10];
  float* out = (float*)d_out;
  char* wsb  = (char*)d_ws;

  unsigned short* xg = (unsigned short*)(wsb + B_XG);

  prep<<<252, 256, 0, stream>>>(dWih, dWhh, dbih, dbhh, eWih, eWhh, ebih, ebhh, fcW, fcb, wsb);
  // time-split: all 512 samples per recurrent dispatch (2 blocks/CU),
  // xg buffer reused for each 150-step half (61.44 MB, same footprint as before)
  pre<<<512, 512, 0, stream>>>(x, wsb, xg, 0);
  recurrent<<<512, 512, 0, stream>>>(xg, wsb, 0);
  pre<<<512, 512, 0, stream>>>(x, wsb, xg, 150);
  recurrent<<<512, 512, 0, stream>>>(xg, wsb, 1);
  emit<<<dim3(512, 2), 192, 0, stream>>>(wsb, fcW, fcb, out);
}